// Round 1
// 219.678 us; speedup vs baseline: 1.1634x; 1.1634x over previous
//
#include <hip/hip_runtime.h>
#include <cstdint>
#include <cstddef>

#define B_    8
#define N_    2048
#define FIN   128
#define FOUT  64
#define ALPHA 0.2f
#define LOG2E 1.4426950408889634f

typedef __attribute__((ext_vector_type(8))) _Float16 half8;
typedef __attribute__((ext_vector_type(4))) _Float16 half4;
typedef __attribute__((ext_vector_type(4))) float float4v;

// ---------------------------------------------------------------------------
// Kernel 0: W [128][64] fp32 -> WtG fp16, transposed [f][k], split hi/lo
// planes (error-compensated fp16: v = hi + lo exactly to fp32 precision).
// Tiny (32 KB out), L2-hot input, coalesced 2B stores (o is linear out idx).
// ---------------------------------------------------------------------------
__global__ __launch_bounds__(256) void k0_convW(
    const float* __restrict__ W, _Float16* __restrict__ WtG)
{
    int o = blockIdx.x * 256 + threadIdx.x;   // 0..8191, grid 32x256
    int f = o >> 7, k = o & 127;
    float v = W[k * FOUT + f];
    _Float16 hi = (_Float16)v;
    _Float16 lo = (_Float16)(v - (float)hi);
    WtG[o] = hi;                              // plane 0: hi
    WtG[FOUT * FIN + o] = lo;                 // plane 1: lo
}

// ---------------------------------------------------------------------------
// Kernel 1: wh = x @ W via MFMA 16x16x32 f16 with split-fp16 compensation
// (acc = ah*bh + ah*bl + al*bh  ->  fp32-level accuracy, ~2^-21 rel error).
// Block: 32 rows x all 64 features, 4 waves (wave w owns features w*16..+15).
// x tile staged in LDS as hi/lo fp16, row stride 136 (pad 8): A-frag read
// lane (l15,quad) -> bank group 4*(l15+quad) mod 32 = structural-min,
// conflict-free; 16B-aligned for b128.
// s1 = wh@a1, s2 = wh@a2 from the fp32 accumulator (same precision as the
// previous fp32 kernel). whT[b][f][j] stored fp16 for k2's B-operand.
// ---------------------------------------------------------------------------
__global__ __launch_bounds__(256, 2) void k1_wh(
    const float* __restrict__ x, const _Float16* __restrict__ WtG,
    const float* __restrict__ w2, _Float16* __restrict__ whT,
    float* __restrict__ s1, float* __restrict__ s2)
{
    __shared__ __attribute__((aligned(16))) _Float16 xth[32][136];
    __shared__ __attribute__((aligned(16))) _Float16 xtl[32][136];
    __shared__ float s1p[4][32];
    __shared__ float s2p[4][32];

    int t = threadIdx.x, lane = t & 63, w = t >> 6;
    int b = blockIdx.x >> 6;
    int r0 = (blockIdx.x & 63) << 5;          // 32 rows per block
    const float* xb = x + ((size_t)b * N_ + r0) * FIN;

    // --- stage x tile (32x128 fp32 = 16 KB), split to fp16 hi/lo ---
    #pragma unroll
    for (int j = 0; j < 4; ++j) {
        int idx = t + j * 256;                // float4 id, fully coalesced
        int row = idx >> 5;
        int k0 = (idx & 31) * 4;
        float4 v = ((const float4*)xb)[idx];
        float vv[4] = {v.x, v.y, v.z, v.w};
        half4 h, l;
        #pragma unroll
        for (int e = 0; e < 4; ++e) {
            _Float16 hi = (_Float16)vv[e];
            h[e] = hi;
            l[e] = (_Float16)(vv[e] - (float)hi);
        }
        *(half4*)&xth[row][k0] = h;
        *(half4*)&xtl[row][k0] = l;
    }
    __syncthreads();

    int l15 = lane & 15, quad = lane >> 4;
    int f0 = w * 16;

    // B fragments (register-resident, from L2-hot WtG[f][k])
    half8 bh[4], bl[4];
    const _Float16* wgh = WtG + (f0 + l15) * FIN + quad * 8;
    #pragma unroll
    for (int c = 0; c < 4; ++c) {
        bh[c] = *(const half8*)(wgh + c * 32);
        bl[c] = *(const half8*)(wgh + FOUT * FIN + c * 32);
    }
    float a1f = w2[f0 + l15], a2f = w2[FOUT + f0 + l15];

    #pragma unroll
    for (int rt = 0; rt < 2; ++rt) {
        float4v acc = {0.f, 0.f, 0.f, 0.f};
        #pragma unroll
        for (int c = 0; c < 4; ++c) {
            half8 ah = *(const half8*)&xth[rt * 16 + l15][c * 32 + quad * 8];
            half8 al = *(const half8*)&xtl[rt * 16 + l15][c * 32 + quad * 8];
            acc = __builtin_amdgcn_mfma_f32_16x16x32_f16(ah, bh[c], acc, 0, 0, 0);
            acc = __builtin_amdgcn_mfma_f32_16x16x32_f16(ah, bl[c], acc, 0, 0, 0);
            acc = __builtin_amdgcn_mfma_f32_16x16x32_f16(al, bh[c], acc, 0, 0, 0);
        }
        // D: col = f0+l15, row = rt*16 + quad*4 + reg (4 consecutive j -> 8B store)
        half4 hv;
        #pragma unroll
        for (int reg = 0; reg < 4; ++reg) hv[reg] = (_Float16)acc[reg];
        *(half4*)(whT + ((size_t)b * FOUT + f0 + l15) * N_ + r0 + rt * 16 + quad * 4) = hv;

        // s1/s2 partials: reduce over the 16 features (l15) per row
        #pragma unroll
        for (int reg = 0; reg < 4; ++reg) {
            float v1 = acc[reg] * a1f;
            float v2 = acc[reg] * a2f;
            #pragma unroll
            for (int m = 1; m <= 8; m <<= 1) {
                v1 += __shfl_xor(v1, m);
                v2 += __shfl_xor(v2, m);
            }
            if (l15 == 0) {
                s1p[w][rt * 16 + quad * 4 + reg] = v1;
                s2p[w][rt * 16 + quad * 4 + reg] = v2;
            }
        }
    }
    __syncthreads();
    if (t < 32) {
        float v = s1p[0][t] + s1p[1][t] + s1p[2][t] + s1p[3][t];
        s1[(size_t)b * N_ + r0 + t] = v;
    } else if (t < 64) {
        int r = t - 32;
        float v = s2p[0][r] + s2p[1][r] + s2p[2][r] + s2p[3][r];
        s2[(size_t)b * N_ + r0 + r] = v;
    }
}

// ---------------------------------------------------------------------------
// Kernel 2: flash-style masked softmax + PV via MFMA (structure unchanged
// from the proven version; p-phase VALU trimmed ~23%):
//   t2 = max(c1 + u, c2 + alpha*u) with c1=(s1-mh)*log2e, c2=(a*s1-mh)*log2e,
//   u = s2*log2e  -> leaky+shift+log2e folded into 2 add + 1 max.
//   p = v_exp_f32(t2); mask -> exact 0 AFTER exp (no NEG_BIG, no -76 clamp).
// ---------------------------------------------------------------------------
__global__ __launch_bounds__(256, 4) void k2_attn(
    const int* __restrict__ adj, const _Float16* __restrict__ whT,
    const float* __restrict__ s1, const float* __restrict__ s2,
    float* __restrict__ out)
{
    __shared__ __attribute__((aligned(16))) _Float16 pT[16][520];
    __shared__ float lL[16];
    __shared__ float smaxL[4];

    int t = threadIdx.x, lane = t & 63, w = t >> 6;
    int b = blockIdx.x >> 7;
    int i0 = (blockIdx.x & 127) << 4;

    // --- exact S2MAX over batch b (8 KB, L2-hot) ---
    const float4* s2v = (const float4*)(s2 + (size_t)b * N_);
    float4 ua_ = s2v[t], ub_ = s2v[t + 256];
    float vm = fmaxf(fmaxf(fmaxf(ua_.x, ua_.y), fmaxf(ua_.z, ua_.w)),
                     fmaxf(fmaxf(ub_.x, ub_.y), fmaxf(ub_.z, ub_.w)));
    #pragma unroll
    for (int m = 32; m >= 1; m >>= 1) vm = fmaxf(vm, __shfl_xor(vm, m));
    if (lane == 0) smaxL[w] = vm;
    __syncthreads();
    float s2max = fmaxf(fmaxf(smaxL[0], smaxL[1]), fmaxf(smaxL[2], smaxL[3]));

    int l15 = lane & 15, quad = lane >> 4;
    int f0 = w * 16;

    // per-row folded constants (wave w owns rows w*4..w*4+3)
    float c1[4], c2[4], lacc[4];
    #pragma unroll
    for (int rr = 0; rr < 4; ++rr) {
        float sv = s1[(size_t)b * N_ + i0 + w * 4 + rr];   // wave-uniform
        float mm = sv + s2max;
        float mh = fmaxf(mm, ALPHA * mm);    // leaky(s1_i + s2max) >= row max
        c1[rr] = (sv - mh) * LOG2E;
        c2[rr] = (ALPHA * sv - mh) * LOG2E;
        lacc[rr] = 0.f;
    }

    float4v acc = {0.f, 0.f, 0.f, 0.f};
    const _Float16* wB = whT + ((size_t)b * FOUT + f0 + l15) * N_ + quad * 8;

    for (int jc = 0; jc < N_; jc += 512) {
        // s2 chunk: 8 consecutive floats per lane, reused across 4 rows
        const float* s2c = s2 + (size_t)b * N_ + jc + lane * 8;
        float4 sa = *(const float4*)s2c;
        float4 sb = *(const float4*)(s2c + 4);
        float ss[8] = {sa.x, sa.y, sa.z, sa.w, sb.x, sb.y, sb.z, sb.w};
        float u[8], ual[8];
        #pragma unroll
        for (int e = 0; e < 8; ++e) {
            u[e] = ss[e] * LOG2E;
            ual[e] = u[e] * ALPHA;
        }

        #pragma unroll
        for (int rr = 0; rr < 4; ++rr) {
            int r = w * 4 + rr;
            const int* ap = adj + ((size_t)b * N_ + i0 + r) * N_ + jc + lane * 8;
            int4 aj0 = *(const int4*)ap;
            int4 aj1 = *(const int4*)(ap + 4);
            int aa[8] = {aj0.x, aj0.y, aj0.z, aj0.w, aj1.x, aj1.y, aj1.z, aj1.w};
            half8 pf;
            float ls = 0.f;
            #pragma unroll
            for (int e = 0; e < 8; ++e) {
                float t2 = fmaxf(c1[rr] + u[e], c2[rr] + ual[e]);  // leaky-mh, log2e
#if __has_builtin(__builtin_amdgcn_exp2f)
                float p = __builtin_amdgcn_exp2f(t2);              // raw v_exp_f32
#else
                float p = exp2f(t2);
#endif
                p = (aa[e] > 0) ? p : 0.f;                         // mask -> exact 0
                ls += p;
                pf[e] = (_Float16)p;
            }
            lacc[rr] += ls;
            *(half8*)&pT[r][lane * 8] = pf;                        // contiguous b128
        }

        if (jc == N_ - 512) {
            // final row-sum reduction, before the barrier that publishes pT
            #pragma unroll
            for (int rr = 0; rr < 4; ++rr) {
                float v = lacc[rr];
                #pragma unroll
                for (int m = 32; m >= 1; m >>= 1) v += __shfl_xor(v, m);
                if (lane == 0) lL[w * 4 + rr] = v;
            }
        }
        __syncthreads();

        // MFMA phase: wave w's 16-feature group, K-chunk of 512
        const _Float16* wp = wB + jc;
        #pragma unroll
        for (int kk = 0; kk < 16; ++kk) {
            half8 af = *(const half8*)&pT[l15][kk * 32 + quad * 8];
            half8 bf = *(const half8*)(wp + kk * 32);
            acc = __builtin_amdgcn_mfma_f32_16x16x32_f16(af, bf, acc, 0, 0, 0);
        }
        __syncthreads();
    }

    // epilogue: normalize, ELU, store. D: row=quad*4+reg, col=f0+l15
    #pragma unroll
    for (int reg = 0; reg < 4; ++reg) {
        int row = quad * 4 + reg;
        float val = acc[reg] / lL[row];
        val = (val > 0.f) ? val : (__expf(val) - 1.f);   // ELU
        out[((size_t)b * N_ + i0 + row) * FOUT + f0 + l15] = val;
    }
}

// ---------------------------------------------------------------------------
extern "C" void kernel_launch(void* const* d_in, const int* in_sizes, int n_in,
                              void* d_out, int out_size, void* d_ws, size_t ws_size,
                              hipStream_t stream) {
    const float* x   = (const float*)d_in[0];
    const int*   adj = (const int*)d_in[1];
    const float* W   = (const float*)d_in[2];
    const float* w2  = (const float*)d_in[3];
    float* out = (float*)d_out;

    _Float16* whT = (_Float16*)d_ws;                                  // 2 MiB
    float* s1 = (float*)((char*)d_ws + (size_t)B_ * FOUT * N_ * 2);   // 64 KiB
    float* s2 = s1 + (size_t)B_ * N_;                                 // 64 KiB
    _Float16* WtG = (_Float16*)(s2 + (size_t)B_ * N_);                // 32 KiB (hi+lo)

    k0_convW<<<32, 256, 0, stream>>>(W, WtG);
    k1_wh<<<(B_ * N_) / 32, 256, 0, stream>>>(x, WtG, w2, whT, s1, s2);
    k2_attn<<<(B_ * N_) / 16, 256, 0, stream>>>(adj, whT, s1, s2, out);
}